// Round 1
// baseline (2098.470 us; speedup 1.0000x reference)
//
#include <hip/hip_runtime.h>
#include <math.h>

// ---------------------------------------------------------------------------
// Problem constants
// ---------------------------------------------------------------------------
#define NB   8
#define NC   512
#define SP   4096              // 64*64 spatial
#define TOT  16777216L         // NB*NC*SP
static const double PI_D = 3.14159265358979323846;

// ws layout (float units)
#define OFF_BUFA 0L
#define OFF_BUFB 16777216L
#define OFF_H1   33554432L            // NB*128*SP = 4194304
#define OFF_H2   37748736L
#define OFF_AK   41943040L            // 512*512
#define OFF_AC   (OFF_AK + 262144L)   // 64*64
#define OFF_G    (OFF_AC + 4096L)     // 4*128*512
#define OFF_W2T  (OFF_G + 262144L)    // 4*9*128*128 = 589824
#define OFF_HIST (OFF_W2T + 589824L)  // hist1 4096 + hist2 4096 + hist3 2048 (u32)
#define OFF_SEL  (OFF_HIST + 10240L)  // u32[16]
#define OFF_THR  (OFF_SEL + 16L)      // float[4]

// ---------------------------------------------------------------------------
// DCT matrices (orthonormal DCT-II), double-precision build
// ---------------------------------------------------------------------------
__global__ void k_build_mats(float* __restrict__ Ak, float* __restrict__ Ac) {
    int idx = blockIdx.x * 256 + threadIdx.x;
    if (idx < 512 * 512) {
        int i = idx >> 9, j = idx & 511;
        double v = cos((double)i * ((double)j + 0.5) * (PI_D / 512.0)) * sqrt(2.0 / 512.0);
        if (i == 0) v *= (1.0 / sqrt(2.0));
        Ak[idx] = (float)v;
    }
    if (idx < 64 * 64) {
        int i = idx >> 6, j = idx & 63;
        double v = cos((double)i * ((double)j + 0.5) * (PI_D / 64.0)) * sqrt(2.0 / 64.0);
        if (i == 0) v *= (1.0 / sqrt(2.0));
        Ac[idx] = (float)v;
    }
}

__global__ void k_zero(unsigned* __restrict__ p, int n) {
    int i = blockIdx.x * 256 + threadIdx.x;
    if (i < n) p[i] = 0u;
}

// G[i][o][k] = sum_c W1[i][o][c] * Ak[k][c]   (fuses IDCT_C into conv1)
__global__ void k_G(const float* __restrict__ W1, const float* __restrict__ Ak,
                    float* __restrict__ G) {
    int idx = blockIdx.x * 256 + threadIdx.x;   // 4*128*512
    int k = idx & 511, o = (idx >> 9) & 127, i = idx >> 16;
    const float* w = W1 + ((long)i * 128 + o) * 512;
    const float* a = Ak + (long)k * 512;
    float s = 0.f;
    for (int c = 0; c < 512; ++c) s += w[c] * a[c];
    G[idx] = s;
}

// W2t[i][t][ci][o] = W2[i][o][ci][t]
__global__ void k_W2t(const float* __restrict__ W2, float* __restrict__ W2t) {
    int idx = blockIdx.x * 256 + threadIdx.x;
    if (idx >= 4 * 9 * 128 * 128) return;
    int o = idx & 127;
    int r = idx >> 7;
    int ci = r & 127;
    r >>= 7;                  // r = i*9 + t
    int t = r % 9, i = r / 9;
    W2t[idx] = W2[(((long)i * 128 + o) * 128 + ci) * 9 + t];
}

// ---------------------------------------------------------------------------
// 64x64 tile two-stage transform (forward DCT over N then M / inverse over
// N then M with coefficient masking). One block per (b, c) tile.
// ---------------------------------------------------------------------------
template <bool FWD, bool MASK>
__global__ __launch_bounds__(256) void k_tile(const float* __restrict__ in,
                                              float* __restrict__ out,
                                              const float* __restrict__ A64,
                                              const float* __restrict__ thrp, int ti) {
    __shared__ __align__(16) float Ms[64][68];
    __shared__ __align__(16) float Ts[64][68];
    __shared__ __align__(16) float Ss[64][68];
    const int tid = threadIdx.x;
    const long tile = blockIdx.x;
    const float* __restrict__ src = in + tile * 4096;
    float* __restrict__ dst = out + tile * 4096;
    float thr = 0.f;
    if (MASK) thr = thrp[ti];
    for (int idx = tid; idx < 4096; idx += 256) {
        int r = idx >> 6, c = idx & 63;
        float a = A64[idx];
        if (FWD) Ms[c][r] = a; else Ms[r][c] = a;
        float v = src[idx];
        if (MASK) v = (fabsf(v) >= thr) ? v : 0.f;
        Ts[r][c] = v;
    }
    __syncthreads();
    const int tx = tid & 15, ty = tid >> 4;
    float acc[4][4];
#pragma unroll
    for (int i = 0; i < 4; ++i)
#pragma unroll
        for (int j = 0; j < 4; ++j) acc[i][j] = 0.f;
    // stage 1: S[r][c] = sum_j Ts[r][j] * Ms[j][c]
#pragma unroll 4
    for (int j = 0; j < 64; ++j) {
        float4 bv = *(const float4*)&Ms[j][tx * 4];
        float a0 = Ts[ty * 4 + 0][j], a1 = Ts[ty * 4 + 1][j];
        float a2 = Ts[ty * 4 + 2][j], a3 = Ts[ty * 4 + 3][j];
        acc[0][0] += a0 * bv.x; acc[0][1] += a0 * bv.y; acc[0][2] += a0 * bv.z; acc[0][3] += a0 * bv.w;
        acc[1][0] += a1 * bv.x; acc[1][1] += a1 * bv.y; acc[1][2] += a1 * bv.z; acc[1][3] += a1 * bv.w;
        acc[2][0] += a2 * bv.x; acc[2][1] += a2 * bv.y; acc[2][2] += a2 * bv.z; acc[2][3] += a2 * bv.w;
        acc[3][0] += a3 * bv.x; acc[3][1] += a3 * bv.y; acc[3][2] += a3 * bv.z; acc[3][3] += a3 * bv.w;
    }
#pragma unroll
    for (int i = 0; i < 4; ++i) {
        float4 v = make_float4(acc[i][0], acc[i][1], acc[i][2], acc[i][3]);
        *(float4*)&Ss[ty * 4 + i][tx * 4] = v;
    }
    __syncthreads();
    // stage 2: out[r2][c] = sum_j Ms[j][r2] * Ss[j][c]
#pragma unroll
    for (int i = 0; i < 4; ++i)
#pragma unroll
        for (int j = 0; j < 4; ++j) acc[i][j] = 0.f;
#pragma unroll 4
    for (int j = 0; j < 64; ++j) {
        float4 av = *(const float4*)&Ms[j][ty * 4];
        float4 sv = *(const float4*)&Ss[j][tx * 4];
        acc[0][0] += av.x * sv.x; acc[0][1] += av.x * sv.y; acc[0][2] += av.x * sv.z; acc[0][3] += av.x * sv.w;
        acc[1][0] += av.y * sv.x; acc[1][1] += av.y * sv.y; acc[1][2] += av.y * sv.z; acc[1][3] += av.y * sv.w;
        acc[2][0] += av.z * sv.x; acc[2][1] += av.z * sv.y; acc[2][2] += av.z * sv.z; acc[2][3] += av.z * sv.w;
        acc[3][0] += av.w * sv.x; acc[3][1] += av.w * sv.y; acc[3][2] += av.w * sv.z; acc[3][3] += av.w * sv.w;
    }
#pragma unroll
    for (int i = 0; i < 4; ++i) {
        float4 v = make_float4(acc[i][0], acc[i][1], acc[i][2], acc[i][3]);
        *(float4*)&dst[(ty * 4 + i) * 64 + tx * 4] = v;
    }
}

// ---------------------------------------------------------------------------
// Generic GEMM:  C[g] (Mr x 4096) = act(A (Mr x K) * B[g] (K x 4096) + bias)
// M-tile 128 (8x4 per thread), N-tile 64, K-chunk 16. ld = 4096 everywhere.
// ---------------------------------------------------------------------------
__global__ __launch_bounds__(256) void k_gemm(const float* __restrict__ A,
                                              const float* __restrict__ Bm,
                                              float* __restrict__ Cm, int K,
                                              long sBg, long sCg,
                                              const float* __restrict__ bias, int relu) {
    const int g = blockIdx.z;
    const int m0 = blockIdx.y * 128, n0 = blockIdx.x * 64;
    const float* __restrict__ Bp = Bm + (long)g * sBg;
    float* __restrict__ Cp = Cm + (long)g * sCg;
    __shared__ __align__(16) float As[16][132];
    __shared__ __align__(16) float Bs[16][68];
    const int tid = threadIdx.x;
    const int tx = tid & 15, ty = tid >> 4;
    float acc[2][4][4];
#pragma unroll
    for (int h = 0; h < 2; ++h)
#pragma unroll
        for (int i = 0; i < 4; ++i)
#pragma unroll
            for (int j = 0; j < 4; ++j) acc[h][i][j] = 0.f;
    for (int k0 = 0; k0 < K; k0 += 16) {
#pragma unroll
        for (int l = 0; l < 8; ++l) {
            int idx = tid + l * 256;
            int kk = idx & 15, mm = idx >> 4;
            As[kk][mm] = A[(long)(m0 + mm) * K + (k0 + kk)];
        }
#pragma unroll
        for (int l = 0; l < 4; ++l) {
            int idx = tid + l * 256;
            int nn = idx & 63, kk = idx >> 6;
            Bs[kk][nn] = Bp[(long)(k0 + kk) * 4096 + (n0 + nn)];
        }
        __syncthreads();
#pragma unroll
        for (int kk = 0; kk < 16; ++kk) {
            float4 a0 = *(const float4*)&As[kk][ty * 4];
            float4 a1 = *(const float4*)&As[kk][64 + ty * 4];
            float4 bv = *(const float4*)&Bs[kk][tx * 4];
            float am[2][4] = {{a0.x, a0.y, a0.z, a0.w}, {a1.x, a1.y, a1.z, a1.w}};
            float bn[4] = {bv.x, bv.y, bv.z, bv.w};
#pragma unroll
            for (int h = 0; h < 2; ++h)
#pragma unroll
                for (int i = 0; i < 4; ++i)
#pragma unroll
                    for (int j = 0; j < 4; ++j) acc[h][i][j] += am[h][i] * bn[j];
        }
        __syncthreads();
    }
#pragma unroll
    for (int h = 0; h < 2; ++h)
#pragma unroll
        for (int i = 0; i < 4; ++i) {
            int m = m0 + h * 64 + ty * 4 + i;
            float4 v = make_float4(acc[h][i][0], acc[h][i][1], acc[h][i][2], acc[h][i][3]);
            if (bias) {
                float bb = bias[m];
                v.x += bb; v.y += bb; v.z += bb; v.w += bb;
                if (relu) {
                    v.x = fmaxf(v.x, 0.f); v.y = fmaxf(v.y, 0.f);
                    v.z = fmaxf(v.z, 0.f); v.w = fmaxf(v.w, 0.f);
                }
            }
            *(float4*)&Cp[(long)m * 4096 + n0 + tx * 4] = v;
        }
}

// ---------------------------------------------------------------------------
// conv2: 3x3, dilation 2, pad 2 (same), 128->128, implicit GEMM K = 9*128.
// One block per (b, y-row): 128 o x 64 x outputs.
// ---------------------------------------------------------------------------
__global__ __launch_bounds__(256) void k_conv2(const float* __restrict__ h1,
                                               const float* __restrict__ W2t,
                                               const float* __restrict__ b2,
                                               float* __restrict__ h2) {
    const int b = blockIdx.z;
    const int y = blockIdx.x;
    const float* __restrict__ hb = h1 + (long)b * 128 * 4096;
    __shared__ __align__(16) float As[16][132];
    __shared__ __align__(16) float Bs[16][68];
    const int tid = threadIdx.x;
    const int tx = tid & 15, ty = tid >> 4;
    float acc[2][4][4];
#pragma unroll
    for (int h = 0; h < 2; ++h)
#pragma unroll
        for (int i = 0; i < 4; ++i)
#pragma unroll
            for (int j = 0; j < 4; ++j) acc[h][i][j] = 0.f;
    for (int ch = 0; ch < 72; ++ch) {
        const int t = ch >> 3;
        const int i0 = (ch & 7) * 16;
        const int ky = t / 3, kx = t - 3 * ky;
        const int yy = y + 2 * ky - 2;
        const bool rowok = (unsigned)yy < 64u;
        const int dx = 2 * kx - 2;
#pragma unroll
        for (int l = 0; l < 8; ++l) {
            int idx = tid + l * 256;
            int kk = idx & 15, mm = idx >> 4;
            As[kk][mm] = W2t[((long)t * 128 + i0 + kk) * 128 + mm];
        }
#pragma unroll
        for (int l = 0; l < 4; ++l) {
            int idx = tid + l * 256;
            int nn = idx & 63, kk = idx >> 6;
            int xx = nn + dx;
            float v = 0.f;
            if (rowok && (unsigned)xx < 64u)
                v = hb[((long)(i0 + kk) * 64 + yy) * 64 + xx];
            Bs[kk][nn] = v;
        }
        __syncthreads();
#pragma unroll
        for (int kk = 0; kk < 16; ++kk) {
            float4 a0 = *(const float4*)&As[kk][ty * 4];
            float4 a1 = *(const float4*)&As[kk][64 + ty * 4];
            float4 bv = *(const float4*)&Bs[kk][tx * 4];
            float am[2][4] = {{a0.x, a0.y, a0.z, a0.w}, {a1.x, a1.y, a1.z, a1.w}};
            float bn[4] = {bv.x, bv.y, bv.z, bv.w};
#pragma unroll
            for (int h = 0; h < 2; ++h)
#pragma unroll
                for (int i = 0; i < 4; ++i)
#pragma unroll
                    for (int j = 0; j < 4; ++j) acc[h][i][j] += am[h][i] * bn[j];
        }
        __syncthreads();
    }
#pragma unroll
    for (int h = 0; h < 2; ++h)
#pragma unroll
        for (int i = 0; i < 4; ++i) {
            int m = h * 64 + ty * 4 + i;
            float bb = b2[m];
            float4 v = make_float4(fmaxf(acc[h][i][0] + bb, 0.f), fmaxf(acc[h][i][1] + bb, 0.f),
                                   fmaxf(acc[h][i][2] + bb, 0.f), fmaxf(acc[h][i][3] + bb, 0.f));
            *(float4*)&h2[(((long)b * 128 + m) * 64 + y) * 64 + tx * 4] = v;
        }
}

// ---------------------------------------------------------------------------
// Exact 4-way radix select on |D| bit patterns (3 levels: 12/10/9 bits)
// ---------------------------------------------------------------------------
__global__ __launch_bounds__(256) void k_hist1(const float4* __restrict__ D, unsigned* __restrict__ g) {
    __shared__ unsigned h[4096];
    for (int i = threadIdx.x; i < 4096; i += 256) h[i] = 0u;
    __syncthreads();
    const long n4 = TOT / 4;
    for (long idx = (long)blockIdx.x * 256 + threadIdx.x; idx < n4; idx += (long)gridDim.x * 256) {
        float4 v = D[idx];
        atomicAdd(&h[__float_as_uint(fabsf(v.x)) >> 19], 1u);
        atomicAdd(&h[__float_as_uint(fabsf(v.y)) >> 19], 1u);
        atomicAdd(&h[__float_as_uint(fabsf(v.z)) >> 19], 1u);
        atomicAdd(&h[__float_as_uint(fabsf(v.w)) >> 19], 1u);
    }
    __syncthreads();
    for (int i = threadIdx.x; i < 4096; i += 256) {
        unsigned c = h[i];
        if (c) atomicAdd(&g[i], c);
    }
}

__global__ void k_scan1(const unsigned* __restrict__ hist, unsigned* __restrict__ sel) {
    __shared__ unsigned chunk[256];
    __shared__ unsigned above[256];
    const int t = threadIdx.x;
    unsigned s = 0;
#pragma unroll
    for (int j = 0; j < 16; ++j) s += hist[t * 16 + j];
    chunk[t] = s;
    __syncthreads();
    if (t == 0) {
        unsigned a = 0;
        for (int c = 255; c >= 0; --c) { above[c] = a; a += chunk[c]; }
    }
    __syncthreads();
    const unsigned kv[4] = {4194304u, 1048576u, 262144u, 65536u};
    unsigned run = above[t];
    for (int j = 15; j >= 0; --j) {
        unsigned bin = t * 16 + j;
        unsigned hb = hist[bin];
        unsigned Sab = run;
        run += hb;
#pragma unroll
        for (int i = 0; i < 4; ++i)
            if (run >= kv[i] && Sab < kv[i]) { sel[i] = bin; sel[4 + i] = kv[i] - Sab; }
    }
}

__global__ __launch_bounds__(256) void k_hist2(const float4* __restrict__ D,
                                               const unsigned* __restrict__ sel,
                                               unsigned* __restrict__ g2) {
    __shared__ unsigned h[4096];
    for (int i = threadIdx.x; i < 4096; i += 256) h[i] = 0u;
    __syncthreads();
    const unsigned p0 = sel[0], p1 = sel[1], p2 = sel[2], p3 = sel[3];
    const long n4 = TOT / 4;
    for (long idx = (long)blockIdx.x * 256 + threadIdx.x; idx < n4; idx += (long)gridDim.x * 256) {
        float4 v = D[idx];
        float f[4] = {v.x, v.y, v.z, v.w};
#pragma unroll
        for (int q = 0; q < 4; ++q) {
            unsigned u = __float_as_uint(fabsf(f[q]));
            unsigned pre = u >> 19, mid = (u >> 9) & 1023u;
            if (pre == p0) atomicAdd(&h[mid], 1u);
            if (pre == p1) atomicAdd(&h[1024 + mid], 1u);
            if (pre == p2) atomicAdd(&h[2048 + mid], 1u);
            if (pre == p3) atomicAdd(&h[3072 + mid], 1u);
        }
    }
    __syncthreads();
    for (int i = threadIdx.x; i < 4096; i += 256) {
        unsigned c = h[i];
        if (c) atomicAdd(&g2[i], c);
    }
}

__global__ void k_scan2(const unsigned* __restrict__ hist2, unsigned* __restrict__ sel) {
    __shared__ unsigned chunk[256];
    __shared__ unsigned above[256];
    const int t = threadIdx.x;
    for (int i = 0; i < 4; ++i) {
        const unsigned* h = hist2 + i * 1024;
        unsigned r = sel[4 + i];
        unsigned s = h[t * 4] + h[t * 4 + 1] + h[t * 4 + 2] + h[t * 4 + 3];
        chunk[t] = s;
        __syncthreads();
        if (t == 0) {
            unsigned a = 0;
            for (int c = 255; c >= 0; --c) { above[c] = a; a += chunk[c]; }
        }
        __syncthreads();
        unsigned run = above[t];
        for (int j = 3; j >= 0; --j) {
            unsigned bin = t * 4 + j;
            unsigned hb = h[bin];
            unsigned Sab = run;
            run += hb;
            if (run >= r && Sab < r) { sel[8 + i] = bin; sel[12 + i] = r - Sab; }
        }
        __syncthreads();
    }
}

__global__ __launch_bounds__(256) void k_hist3(const float4* __restrict__ D,
                                               const unsigned* __restrict__ sel,
                                               unsigned* __restrict__ g3) {
    __shared__ unsigned h[2048];
    for (int i = threadIdx.x; i < 2048; i += 256) h[i] = 0u;
    __syncthreads();
    unsigned pre2[4];
#pragma unroll
    for (int i = 0; i < 4; ++i) pre2[i] = (sel[i] << 10) | sel[8 + i];
    const long n4 = TOT / 4;
    for (long idx = (long)blockIdx.x * 256 + threadIdx.x; idx < n4; idx += (long)gridDim.x * 256) {
        float4 v = D[idx];
        float f[4] = {v.x, v.y, v.z, v.w};
#pragma unroll
        for (int q = 0; q < 4; ++q) {
            unsigned u = __float_as_uint(fabsf(f[q]));
            unsigned p = u >> 9, low = u & 511u;
            if (p == pre2[0]) atomicAdd(&h[low], 1u);
            if (p == pre2[1]) atomicAdd(&h[512 + low], 1u);
            if (p == pre2[2]) atomicAdd(&h[1024 + low], 1u);
            if (p == pre2[3]) atomicAdd(&h[1536 + low], 1u);
        }
    }
    __syncthreads();
    for (int i = threadIdx.x; i < 2048; i += 256) {
        unsigned c = h[i];
        if (c) atomicAdd(&g3[i], c);
    }
}

__global__ void k_scan3(const unsigned* __restrict__ hist3, const unsigned* __restrict__ sel,
                        float* __restrict__ thr) {
    __shared__ unsigned chunk[256];
    __shared__ unsigned above[256];
    const int t = threadIdx.x;
    for (int i = 0; i < 4; ++i) {
        const unsigned* h = hist3 + i * 512;
        unsigned r = sel[12 + i];
        unsigned s = h[t * 2] + h[t * 2 + 1];
        chunk[t] = s;
        __syncthreads();
        if (t == 0) {
            unsigned a = 0;
            for (int c = 255; c >= 0; --c) { above[c] = a; a += chunk[c]; }
        }
        __syncthreads();
        unsigned run = above[t];
        for (int j = 1; j >= 0; --j) {
            unsigned bin = t * 2 + j;
            unsigned hb = h[bin];
            unsigned Sab = run;
            run += hb;
            if (run >= r && Sab < r) {
                unsigned bits = (sel[i] << 19) | (sel[8 + i] << 9) | bin;
                thr[i] = __uint_as_float(bits);
            }
        }
        __syncthreads();
    }
}

// ---------------------------------------------------------------------------
// Final: channel softmax over 512 (=4x128 concat) + residual gating, in-place
// ---------------------------------------------------------------------------
__global__ __launch_bounds__(256) void k_final(const float* __restrict__ x, float* __restrict__ io) {
    const int bm = blockIdx.x;            // 0..511
    const int b = bm >> 6, m = bm & 63;
    const int n = threadIdx.x & 63, grp = threadIdx.x >> 6;   // grp 0..3
    const long base = ((long)b * 512) * 4096 + m * 64 + n;
    __shared__ float red[4][64];
    float mx = -1e30f;
    for (int c = grp * 128; c < grp * 128 + 128; ++c)
        mx = fmaxf(mx, io[base + (long)c * 4096]);
    red[grp][n] = mx;
    __syncthreads();
    const float M = fmaxf(fmaxf(red[0][n], red[1][n]), fmaxf(red[2][n], red[3][n]));
    __syncthreads();
    float s = 0.f;
    for (int c = grp * 128; c < grp * 128 + 128; ++c)
        s += __expf(io[base + (long)c * 4096] - M);
    red[grp][n] = s;
    __syncthreads();
    const float S = red[0][n] + red[1][n] + red[2][n] + red[3][n];
    const float inv = 1.0f / S;
    for (int c = grp * 128; c < grp * 128 + 128; ++c) {
        long a = base + (long)c * 4096;
        float w = __expf(io[a] - M) * inv;
        float xv = x[a];
        io[a] = xv * w + xv;
    }
}

// ---------------------------------------------------------------------------
extern "C" void kernel_launch(void* const* d_in, const int* in_sizes, int n_in,
                              void* d_out, int out_size, void* d_ws, size_t ws_size,
                              hipStream_t stream) {
    (void)in_sizes; (void)n_in; (void)out_size; (void)ws_size;
    const float* x  = (const float*)d_in[0];
    const float* W1 = (const float*)d_in[1];
    const float* b1 = (const float*)d_in[2];
    const float* W2 = (const float*)d_in[3];
    const float* b2 = (const float*)d_in[4];
    const float* W3 = (const float*)d_in[5];
    const float* b3 = (const float*)d_in[6];
    float* out = (float*)d_out;
    float* ws = (float*)d_ws;

    float* bufA = ws + OFF_BUFA;
    float* bufB = ws + OFF_BUFB;
    float* h1   = ws + OFF_H1;
    float* h2   = ws + OFF_H2;
    float* Ak   = ws + OFF_AK;
    float* Ac   = ws + OFF_AC;
    float* G    = ws + OFF_G;
    float* W2t  = ws + OFF_W2T;
    unsigned* hist1 = (unsigned*)(ws + OFF_HIST);
    unsigned* hist2 = hist1 + 4096;
    unsigned* hist3 = hist2 + 4096;
    unsigned* sel   = (unsigned*)(ws + OFF_SEL);
    float* thr      = ws + OFF_THR;

    // setup
    k_build_mats<<<1024, 256, 0, stream>>>(Ak, Ac);
    k_zero<<<40, 256, 0, stream>>>(hist1, 10240);
    k_G<<<1024, 256, 0, stream>>>(W1, Ak, G);
    k_W2t<<<2304, 256, 0, stream>>>(W2, W2t);

    // forward DCT: M,N tile transforms then C-dim GEMM
    k_tile<true, false><<<4096, 256, 0, stream>>>(x, bufA, Ac, nullptr, 0);
    k_gemm<<<dim3(64, 4, 8), 256, 0, stream>>>(Ak, bufA, bufB, 512,
                                               512L * 4096, 512L * 4096, nullptr, 0);

    // exact 4-way top-k thresholds on |D|
    k_hist1<<<256, 256, 0, stream>>>((const float4*)bufB, hist1);
    k_scan1<<<1, 256, 0, stream>>>(hist1, sel);
    k_hist2<<<256, 256, 0, stream>>>((const float4*)bufB, sel, hist2);
    k_scan2<<<1, 256, 0, stream>>>(hist2, sel);
    k_hist3<<<256, 256, 0, stream>>>((const float4*)bufB, sel, hist3);
    k_scan3<<<1, 256, 0, stream>>>(hist3, sel, thr);

    // 4 branches: masked M,N inverse; fused (IDCT_C + conv1); conv2; conv3
    for (int i = 0; i < 4; ++i) {
        k_tile<false, true><<<4096, 256, 0, stream>>>(bufB, bufA, Ac, thr, i);
        k_gemm<<<dim3(64, 1, 8), 256, 0, stream>>>(G + (long)i * 128 * 512, bufA, h1, 512,
                                                   512L * 4096, 128L * 4096, b1 + i * 128, 1);
        k_conv2<<<dim3(64, 1, 8), 256, 0, stream>>>(h1, W2t + (long)i * 147456, b2 + i * 128, h2);
        k_gemm<<<dim3(64, 1, 8), 256, 0, stream>>>(W3 + (long)i * 128 * 128, h2,
                                                   out + (long)i * 128 * 4096, 128,
                                                   128L * 4096, 512L * 4096, b3 + i * 128, 1);
    }

    // softmax gating + residual
    k_final<<<512, 256, 0, stream>>>(x, out);
}

// Round 2
// 771.456 us; speedup vs baseline: 2.7201x; 2.7201x over previous
//
#include <hip/hip_runtime.h>
#include <math.h>

#define NB   8
#define NC   512
#define SP   4096
#define TOT  16777216L
static const double PI_D = 3.14159265358979323846;

typedef short s16x8 __attribute__((ext_vector_type(8)));
typedef float f32x4 __attribute__((ext_vector_type(4)));
typedef unsigned short u16;

// ---------------- ws layout (float units) ----------------
// region A [0,16777216): t fp32; later h1pre bf16 [0,8388608) + X2 bf16 [8388608,16777216)
// region B [16777216,25165824): thi/tlo bf16; later h1 bf16
// region C [25165824,41943040): D fp32; later h2 bf16 in first half
#define OFF_T    0L
#define OFF_H1P  0L
#define OFF_X2   8388608L
#define OFF_THI  16777216L
#define OFF_TLO  20971520L
#define OFF_H1   16777216L
#define OFF_D    25165824L
#define OFF_H2   25165824L
#define OFF_AK   41943040L
#define OFF_AKH  42205184L
#define OFF_AKL  42336256L
#define OFF_ACT  42467328L
#define OFF_GBF  42468352L
#define OFF_W2A  42599424L
#define OFF_W3B  42894336L
#define OFF_HIST 42927104L
#define OFF_SEL  42937344L
#define OFF_THR  42937360L
#define OFF_AC   42937368L

__device__ inline u16 bfr(float x) {
    unsigned u = __float_as_uint(x);
    unsigned r = u + 0x7fffu + ((u >> 16) & 1u);
    return (u16)(r >> 16);
}
__device__ inline float bff(u16 h) { return __uint_as_float(((unsigned)h) << 16); }

#define MFMA(a, b, c) __builtin_amdgcn_mfma_f32_16x16x32_bf16((a), (b), (c), 0, 0, 0)

// ---------------- setup kernels ----------------
__global__ void k_build_mats(float* __restrict__ Ak, u16* __restrict__ Akh, u16* __restrict__ Akl,
                             u16* __restrict__ AcT, float* __restrict__ Ac) {
    int idx = blockIdx.x * 256 + threadIdx.x;
    if (idx < 512 * 512) {
        int i = idx >> 9, j = idx & 511;
        double v = cos((double)i * ((double)j + 0.5) * (PI_D / 512.0)) * sqrt(2.0 / 512.0);
        if (i == 0) v *= (1.0 / sqrt(2.0));
        float f = (float)v;
        Ak[idx] = f;
        u16 h = bfr(f);
        Akh[idx] = h;
        Akl[idx] = bfr(f - bff(h));
    }
    if (idx < 64 * 64) {
        int i = idx >> 6, j = idx & 63;
        double v = cos((double)i * ((double)j + 0.5) * (PI_D / 64.0)) * sqrt(2.0 / 64.0);
        if (i == 0) v *= (1.0 / sqrt(2.0));
        Ac[idx] = (float)v;
        // AcT[n][n'] = Ac[n'][n]
        int n = idx >> 6, np = idx & 63;
        double w = cos((double)np * ((double)n + 0.5) * (PI_D / 64.0)) * sqrt(2.0 / 64.0);
        if (np == 0) w *= (1.0 / sqrt(2.0));
        AcT[idx] = bfr((float)w);
    }
}

__global__ void k_zero(unsigned* __restrict__ p, int n) {
    int i = blockIdx.x * 256 + threadIdx.x;
    if (i < n) p[i] = 0u;
}

// G_bf[i][o][kc] = bf16( sum_c W1[i][o][c] * Ak[kc][c] )
__global__ void k_G_bf(const float* __restrict__ W1, const float* __restrict__ Ak,
                       u16* __restrict__ G) {
    int idx = blockIdx.x * 256 + threadIdx.x;   // 4*128*512
    int kc = idx & 511, oi = idx >> 9;
    const float* w = W1 + (long)oi * 512;
    const float* a = Ak + (long)kc * 512;
    float s = 0.f;
    for (int c = 0; c < 512; ++c) s += w[c] * a[c];
    G[idx] = bfr(s);
}

// W2a[i][o][t*128+ci] = W2[i][o][ci][t];  W3b = cvt(W3)
__global__ void k_wprep(const float* __restrict__ W2, const float* __restrict__ W3,
                        u16* __restrict__ W2a, u16* __restrict__ W3b) {
    int idx = blockIdx.x * 256 + threadIdx.x;
    if (idx < 4 * 128 * 1152) {
        int k = idx % 1152;
        int oi = idx / 1152;         // i*128+o
        int t = k >> 7, ci = k & 127;
        W2a[idx] = bfr(W2[((long)oi * 128 + ci) * 9 + t]);
    }
    if (idx < 65536) W3b[idx] = bfr(W3[idx]);
}

// ---------------- forward 2D DCT tile (fp32, from R1) ----------------
__global__ __launch_bounds__(256) void k_tile_fwd(const float* __restrict__ in,
                                                  float* __restrict__ out,
                                                  const float* __restrict__ A64) {
    __shared__ __align__(16) float Ms[64][68];
    __shared__ __align__(16) float Ts[64][68];
    __shared__ __align__(16) float Ss[64][68];
    const int tid = threadIdx.x;
    const long tile = blockIdx.x;
    const float* __restrict__ src = in + tile * 4096;
    float* __restrict__ dst = out + tile * 4096;
    for (int idx = tid; idx < 4096; idx += 256) {
        int r = idx >> 6, c = idx & 63;
        Ms[c][r] = A64[idx];
        Ts[r][c] = src[idx];
    }
    __syncthreads();
    const int tx = tid & 15, ty = tid >> 4;
    float acc[4][4];
#pragma unroll
    for (int i = 0; i < 4; ++i)
#pragma unroll
        for (int j = 0; j < 4; ++j) acc[i][j] = 0.f;
#pragma unroll 4
    for (int j = 0; j < 64; ++j) {
        float4 bv = *(const float4*)&Ms[j][tx * 4];
        float a0 = Ts[ty * 4 + 0][j], a1 = Ts[ty * 4 + 1][j];
        float a2 = Ts[ty * 4 + 2][j], a3 = Ts[ty * 4 + 3][j];
        acc[0][0] += a0 * bv.x; acc[0][1] += a0 * bv.y; acc[0][2] += a0 * bv.z; acc[0][3] += a0 * bv.w;
        acc[1][0] += a1 * bv.x; acc[1][1] += a1 * bv.y; acc[1][2] += a1 * bv.z; acc[1][3] += a1 * bv.w;
        acc[2][0] += a2 * bv.x; acc[2][1] += a2 * bv.y; acc[2][2] += a2 * bv.z; acc[2][3] += a2 * bv.w;
        acc[3][0] += a3 * bv.x; acc[3][1] += a3 * bv.y; acc[3][2] += a3 * bv.z; acc[3][3] += a3 * bv.w;
    }
#pragma unroll
    for (int i = 0; i < 4; ++i)
        *(float4*)&Ss[ty * 4 + i][tx * 4] = make_float4(acc[i][0], acc[i][1], acc[i][2], acc[i][3]);
    __syncthreads();
#pragma unroll
    for (int i = 0; i < 4; ++i)
#pragma unroll
        for (int j = 0; j < 4; ++j) acc[i][j] = 0.f;
#pragma unroll 4
    for (int j = 0; j < 64; ++j) {
        float4 av = *(const float4*)&Ms[j][ty * 4];
        float4 sv = *(const float4*)&Ss[j][tx * 4];
        acc[0][0] += av.x * sv.x; acc[0][1] += av.x * sv.y; acc[0][2] += av.x * sv.z; acc[0][3] += av.x * sv.w;
        acc[1][0] += av.y * sv.x; acc[1][1] += av.y * sv.y; acc[1][2] += av.y * sv.z; acc[1][3] += av.y * sv.w;
        acc[2][0] += av.z * sv.x; acc[2][1] += av.z * sv.y; acc[2][2] += av.z * sv.z; acc[2][3] += av.z * sv.w;
        acc[3][0] += av.w * sv.x; acc[3][1] += av.w * sv.y; acc[3][2] += av.w * sv.z; acc[3][3] += av.w * sv.w;
    }
#pragma unroll
    for (int i = 0; i < 4; ++i)
        *(float4*)&dst[(ty * 4 + i) * 64 + tx * 4] = make_float4(acc[i][0], acc[i][1], acc[i][2], acc[i][3]);
}

// ---------------- transpose + split: t NCHW fp32 -> thi/tlo NHWC bf16 ----------------
__global__ __launch_bounds__(256) void k_tsplit(const float* __restrict__ t,
                                                u16* __restrict__ thi, u16* __restrict__ tlo) {
    __shared__ float Ls[64][65];
    const int b = blockIdx.z, cg = blockIdx.y, pg = blockIdx.x;
    const int tid = threadIdx.x;
    const float* src = t + ((long)b * 512 + cg * 64) * 4096 + pg * 64;
#pragma unroll
    for (int j = 0; j < 4; ++j) {
        int c = (tid >> 4) + j * 16, p4 = (tid & 15) * 4;
        float4 v = *(const float4*)&src[(long)c * 4096 + p4];
        Ls[c][p4 + 0] = v.x; Ls[c][p4 + 1] = v.y; Ls[c][p4 + 2] = v.z; Ls[c][p4 + 3] = v.w;
    }
    __syncthreads();
#pragma unroll
    for (int j = 0; j < 2; ++j) {
        int idx = tid + j * 256;
        int p = idx >> 3, c8 = idx & 7;
        s16x8 vh, vl;
#pragma unroll
        for (int q = 0; q < 8; ++q) {
            float f = Ls[c8 * 8 + q][p];
            u16 h = bfr(f);
            vh[q] = (short)h;
            vl[q] = (short)bfr(f - bff(h));
        }
        long addr = ((long)b * 4096 + pg * 64 + p) * 512 + cg * 64 + c8 * 8;
        *(s16x8*)&thi[addr] = vh;
        *(s16x8*)&tlo[addr] = vl;
    }
}

// ---------------- C-DCT GEMM, split bf16: D[b][p][kc] = sum_c t[p][c]*Ak[kc][c] ----------------
__global__ __launch_bounds__(256, 2) void k_cgemm(const u16* __restrict__ thi, const u16* __restrict__ tlo,
                                                  const u16* __restrict__ Akh, const u16* __restrict__ Akl,
                                                  float* __restrict__ D) {
    __shared__ __align__(16) short Ph[128 * 40];
    __shared__ __align__(16) short Pl[128 * 40];
    __shared__ __align__(16) short Qh[128 * 40];
    __shared__ __align__(16) short Ql[128 * 40];
    const int b = blockIdx.z;
    const int p0 = blockIdx.y * 128, kc0 = blockIdx.x * 128;
    const int tid = threadIdx.x;
    const int lane = tid & 63, wave = tid >> 6;
    const int fr = lane & 15, qd = lane >> 4;
    const int mq = (wave >> 1) * 64, nq = (wave & 1) * 64;
    f32x4 acc[4][4];
#pragma unroll
    for (int i = 0; i < 4; ++i)
#pragma unroll
        for (int j = 0; j < 4; ++j) acc[i][j] = (f32x4){0.f, 0.f, 0.f, 0.f};
    const u16* Pgh = thi + ((long)b * 4096 + p0) * 512;
    const u16* Pgl = tlo + ((long)b * 4096 + p0) * 512;
    const u16* Qgh = Akh + (long)kc0 * 512;
    const u16* Qgl = Akl + (long)kc0 * 512;
    for (int ch = 0; ch < 16; ++ch) {
        const int k0 = ch * 32;
        __syncthreads();
#pragma unroll
        for (int j = 0; j < 2; ++j) {
            int idx = tid + j * 256;
            int r = idx >> 2, q4 = (idx & 3) * 8;
            *(s16x8*)&Ph[r * 40 + q4] = *(const s16x8*)&Pgh[(long)r * 512 + k0 + q4];
            *(s16x8*)&Pl[r * 40 + q4] = *(const s16x8*)&Pgl[(long)r * 512 + k0 + q4];
            *(s16x8*)&Qh[r * 40 + q4] = *(const s16x8*)&Qgh[(long)r * 512 + k0 + q4];
            *(s16x8*)&Ql[r * 40 + q4] = *(const s16x8*)&Qgl[(long)r * 512 + k0 + q4];
        }
        __syncthreads();
        s16x8 ph[4], pl[4], qh[4], ql[4];
#pragma unroll
        for (int i = 0; i < 4; ++i) {
            ph[i] = *(const s16x8*)&Ph[(mq + 16 * i + fr) * 40 + qd * 8];
            pl[i] = *(const s16x8*)&Pl[(mq + 16 * i + fr) * 40 + qd * 8];
            qh[i] = *(const s16x8*)&Qh[(nq + 16 * i + fr) * 40 + qd * 8];
            ql[i] = *(const s16x8*)&Ql[(nq + 16 * i + fr) * 40 + qd * 8];
        }
#pragma unroll
        for (int i = 0; i < 4; ++i)
#pragma unroll
            for (int j = 0; j < 4; ++j) {
                acc[i][j] = MFMA(ph[i], qh[j], acc[i][j]);
                acc[i][j] = MFMA(ph[i], ql[j], acc[i][j]);
                acc[i][j] = MFMA(pl[i], qh[j], acc[i][j]);
            }
    }
#pragma unroll
    for (int i = 0; i < 4; ++i)
#pragma unroll
        for (int j = 0; j < 4; ++j) {
            int rowb = mq + 16 * i + qd * 4;
            int col = kc0 + nq + 16 * j + fr;
#pragma unroll
            for (int r = 0; r < 4; ++r)
                D[((long)b * 4096 + p0 + rowb + r) * 512 + col] = acc[i][j][r];
        }
}

// ---------------- radix-select (fp32 D, unchanged from R1) ----------------
__global__ __launch_bounds__(256) void k_hist1(const float4* __restrict__ D, unsigned* __restrict__ g) {
    __shared__ unsigned h[4096];
    for (int i = threadIdx.x; i < 4096; i += 256) h[i] = 0u;
    __syncthreads();
    const long n4 = TOT / 4;
    for (long idx = (long)blockIdx.x * 256 + threadIdx.x; idx < n4; idx += (long)gridDim.x * 256) {
        float4 v = D[idx];
        atomicAdd(&h[__float_as_uint(fabsf(v.x)) >> 19], 1u);
        atomicAdd(&h[__float_as_uint(fabsf(v.y)) >> 19], 1u);
        atomicAdd(&h[__float_as_uint(fabsf(v.z)) >> 19], 1u);
        atomicAdd(&h[__float_as_uint(fabsf(v.w)) >> 19], 1u);
    }
    __syncthreads();
    for (int i = threadIdx.x; i < 4096; i += 256) {
        unsigned c = h[i];
        if (c) atomicAdd(&g[i], c);
    }
}

__global__ void k_scan1(const unsigned* __restrict__ hist, unsigned* __restrict__ sel) {
    __shared__ unsigned chunk[256];
    __shared__ unsigned above[256];
    const int t = threadIdx.x;
    unsigned s = 0;
#pragma unroll
    for (int j = 0; j < 16; ++j) s += hist[t * 16 + j];
    chunk[t] = s;
    __syncthreads();
    if (t == 0) {
        unsigned a = 0;
        for (int c = 255; c >= 0; --c) { above[c] = a; a += chunk[c]; }
    }
    __syncthreads();
    const unsigned kv[4] = {4194304u, 1048576u, 262144u, 65536u};
    unsigned run = above[t];
    for (int j = 15; j >= 0; --j) {
        unsigned bin = t * 16 + j;
        unsigned hb = hist[bin];
        unsigned Sab = run;
        run += hb;
#pragma unroll
        for (int i = 0; i < 4; ++i)
            if (run >= kv[i] && Sab < kv[i]) { sel[i] = bin; sel[4 + i] = kv[i] - Sab; }
    }
}

__global__ __launch_bounds__(256) void k_hist2(const float4* __restrict__ D,
                                               const unsigned* __restrict__ sel,
                                               unsigned* __restrict__ g2) {
    __shared__ unsigned h[4096];
    for (int i = threadIdx.x; i < 4096; i += 256) h[i] = 0u;
    __syncthreads();
    const unsigned p0 = sel[0], p1 = sel[1], p2 = sel[2], p3 = sel[3];
    const long n4 = TOT / 4;
    for (long idx = (long)blockIdx.x * 256 + threadIdx.x; idx < n4; idx += (long)gridDim.x * 256) {
        float4 v = D[idx];
        float f[4] = {v.x, v.y, v.z, v.w};
#pragma unroll
        for (int q = 0; q < 4; ++q) {
            unsigned u = __float_as_uint(fabsf(f[q]));
            unsigned pre = u >> 19, mid = (u >> 9) & 1023u;
            if (pre == p0) atomicAdd(&h[mid], 1u);
            if (pre == p1) atomicAdd(&h[1024 + mid], 1u);
            if (pre == p2) atomicAdd(&h[2048 + mid], 1u);
            if (pre == p3) atomicAdd(&h[3072 + mid], 1u);
        }
    }
    __syncthreads();
    for (int i = threadIdx.x; i < 4096; i += 256) {
        unsigned c = h[i];
        if (c) atomicAdd(&g2[i], c);
    }
}

__global__ void k_scan2(const unsigned* __restrict__ hist2, unsigned* __restrict__ sel) {
    __shared__ unsigned chunk[256];
    __shared__ unsigned above[256];
    const int t = threadIdx.x;
    for (int i = 0; i < 4; ++i) {
        const unsigned* h = hist2 + i * 1024;
        unsigned r = sel[4 + i];
        unsigned s = h[t * 4] + h[t * 4 + 1] + h[t * 4 + 2] + h[t * 4 + 3];
        chunk[t] = s;
        __syncthreads();
        if (t == 0) {
            unsigned a = 0;
            for (int c = 255; c >= 0; --c) { above[c] = a; a += chunk[c]; }
        }
        __syncthreads();
        unsigned run = above[t];
        for (int j = 3; j >= 0; --j) {
            unsigned bin = t * 4 + j;
            unsigned hb = h[bin];
            unsigned Sab = run;
            run += hb;
            if (run >= r && Sab < r) { sel[8 + i] = bin; sel[12 + i] = r - Sab; }
        }
        __syncthreads();
    }
}

__global__ __launch_bounds__(256) void k_hist3(const float4* __restrict__ D,
                                               const unsigned* __restrict__ sel,
                                               unsigned* __restrict__ g3) {
    __shared__ unsigned h[2048];
    for (int i = threadIdx.x; i < 2048; i += 256) h[i] = 0u;
    __syncthreads();
    unsigned pre2[4];
#pragma unroll
    for (int i = 0; i < 4; ++i) pre2[i] = (sel[i] << 10) | sel[8 + i];
    const long n4 = TOT / 4;
    for (long idx = (long)blockIdx.x * 256 + threadIdx.x; idx < n4; idx += (long)gridDim.x * 256) {
        float4 v = D[idx];
        float f[4] = {v.x, v.y, v.z, v.w};
#pragma unroll
        for (int q = 0; q < 4; ++q) {
            unsigned u = __float_as_uint(fabsf(f[q]));
            unsigned p = u >> 9, low = u & 511u;
            if (p == pre2[0]) atomicAdd(&h[low], 1u);
            if (p == pre2[1]) atomicAdd(&h[512 + low], 1u);
            if (p == pre2[2]) atomicAdd(&h[1024 + low], 1u);
            if (p == pre2[3]) atomicAdd(&h[1536 + low], 1u);
        }
    }
    __syncthreads();
    for (int i = threadIdx.x; i < 2048; i += 256) {
        unsigned c = h[i];
        if (c) atomicAdd(&g3[i], c);
    }
}

__global__ void k_scan3(const unsigned* __restrict__ hist3, const unsigned* __restrict__ sel,
                        float* __restrict__ thr) {
    __shared__ unsigned chunk[256];
    __shared__ unsigned above[256];
    const int t = threadIdx.x;
    for (int i = 0; i < 4; ++i) {
        const unsigned* h = hist3 + i * 512;
        unsigned r = sel[12 + i];
        unsigned s = h[t * 2] + h[t * 2 + 1];
        chunk[t] = s;
        __syncthreads();
        if (t == 0) {
            unsigned a = 0;
            for (int c = 255; c >= 0; --c) { above[c] = a; a += chunk[c]; }
        }
        __syncthreads();
        unsigned run = above[t];
        for (int j = 1; j >= 0; --j) {
            unsigned bin = t * 2 + j;
            unsigned hb = h[bin];
            unsigned Sab = run;
            run += hb;
            if (run >= r && Sab < r)
                thr[i] = __uint_as_float((sel[i] << 19) | (sel[8 + i] << 9) | bin);
        }
        __syncthreads();
    }
}

// ---------------- conv1 fused with IDCT_C: h1pre[z2][o][p] = sum_kc G[o][kc]*Dm[p][kc] ----------------
__global__ __launch_bounds__(256, 2) void k_conv1(const float* __restrict__ D, const u16* __restrict__ Gb,
                                                  const float* __restrict__ thrp, u16* __restrict__ h1pre) {
    __shared__ __align__(16) short Pt[128 * 40];
    __shared__ __align__(16) short Qt[128 * 40];
    const int b = blockIdx.z, br = blockIdx.y, p0 = blockIdx.x * 128;
    const int z2 = br * 8 + b;
    const float thr = thrp[br];
    const int tid = threadIdx.x;
    const int lane = tid & 63, wave = tid >> 6;
    const int fr = lane & 15, qd = lane >> 4;
    const int mq = (wave >> 1) * 64, nq = (wave & 1) * 64;
    f32x4 acc[4][4];
#pragma unroll
    for (int i = 0; i < 4; ++i)
#pragma unroll
        for (int j = 0; j < 4; ++j) acc[i][j] = (f32x4){0.f, 0.f, 0.f, 0.f};
    const float* Pg = D + ((long)b * 4096 + p0) * 512;
    const u16* Qg = Gb + (long)br * 65536;
    for (int ch = 0; ch < 16; ++ch) {
        const int k0 = ch * 32;
        __syncthreads();
#pragma unroll
        for (int j = 0; j < 2; ++j) {
            int idx = tid + j * 256;
            int r = idx >> 2, q4 = (idx & 3) * 8;
            const float* src = &Pg[(long)r * 512 + k0 + q4];
            float4 v0 = *(const float4*)src;
            float4 v1 = *(const float4*)(src + 4);
            s16x8 m;
            float f[8] = {v0.x, v0.y, v0.z, v0.w, v1.x, v1.y, v1.z, v1.w};
#pragma unroll
            for (int q = 0; q < 8; ++q) m[q] = (short)(fabsf(f[q]) >= thr ? bfr(f[q]) : (u16)0);
            *(s16x8*)&Pt[r * 40 + q4] = m;
            *(s16x8*)&Qt[r * 40 + q4] = *(const s16x8*)&Qg[(long)r * 512 + k0 + q4];
        }
        __syncthreads();
        s16x8 pa[4], qb[4];
#pragma unroll
        for (int i = 0; i < 4; ++i) {
            pa[i] = *(const s16x8*)&Pt[(mq + 16 * i + fr) * 40 + qd * 8];
            qb[i] = *(const s16x8*)&Qt[(nq + 16 * i + fr) * 40 + qd * 8];
        }
#pragma unroll
        for (int i = 0; i < 4; ++i)
#pragma unroll
            for (int j = 0; j < 4; ++j) acc[i][j] = MFMA(pa[i], qb[j], acc[i][j]);
    }
#pragma unroll
    for (int i = 0; i < 4; ++i)
#pragma unroll
        for (int j = 0; j < 4; ++j) {
            int rowb = p0 + mq + 16 * i + qd * 4;        // pixel
            int o = nq + 16 * j + fr;                     // channel
            ushort4 pk;
            pk.x = bfr(acc[i][j][0]); pk.y = bfr(acc[i][j][1]);
            pk.z = bfr(acc[i][j][2]); pk.w = bfr(acc[i][j][3]);
            *(ushort4*)&h1pre[((long)z2 * 128 + o) * 4096 + rowb] = pk;
        }
}

// ---------------- IDCT pass (shared shape): out = P(128-row tiles, k=64) x AcT^T ----------------
// pass1: P=h1pre rows (o*64+y), k=x  -> X2[z2][xo][o][y]
// pass2: P=X2 rows (xo*128+o), k=y   -> h1[z2][yo][xo][o] (+bias+relu)
__global__ __launch_bounds__(256, 2) void k_idct1(const u16* __restrict__ h1pre, const u16* __restrict__ AcT,
                                                  u16* __restrict__ X2) {
    __shared__ __align__(16) short Pt[128 * 72];
    __shared__ __align__(16) short Qt[64 * 72];
    const int b = blockIdx.z, br = blockIdx.y, m0 = blockIdx.x * 128;
    const int z2 = br * 8 + b;
    const int tid = threadIdx.x;
    const int lane = tid & 63, wave = tid >> 6;
    const int fr = lane & 15, qd = lane >> 4;
    const int mq = wave * 32;
    const u16* Pg = h1pre + (long)z2 * 524288 + (long)m0 * 64;
    f32x4 acc[2][4];
#pragma unroll
    for (int i = 0; i < 2; ++i)
#pragma unroll
        for (int j = 0; j < 4; ++j) acc[i][j] = (f32x4){0.f, 0.f, 0.f, 0.f};
#pragma unroll
    for (int j = 0; j < 4; ++j) {
        int idx = tid + j * 256;
        int r = idx >> 3, q8 = (idx & 7) * 8;
        *(s16x8*)&Pt[r * 72 + q8] = *(const s16x8*)&Pg[(long)r * 64 + q8];
    }
#pragma unroll
    for (int j = 0; j < 2; ++j) {
        int idx = tid + j * 256;
        int r = idx >> 3, q8 = (idx & 7) * 8;
        *(s16x8*)&Qt[r * 72 + q8] = *(const s16x8*)&AcT[(long)r * 64 + q8];
    }
    __syncthreads();
#pragma unroll
    for (int ks = 0; ks < 2; ++ks) {
        s16x8 pa[2], qb[4];
#pragma unroll
        for (int i = 0; i < 2; ++i) pa[i] = *(const s16x8*)&Pt[(mq + 16 * i + fr) * 72 + ks * 32 + qd * 8];
#pragma unroll
        for (int j = 0; j < 4; ++j) qb[j] = *(const s16x8*)&Qt[(16 * j + fr) * 72 + ks * 32 + qd * 8];
#pragma unroll
        for (int i = 0; i < 2; ++i)
#pragma unroll
            for (int j = 0; j < 4; ++j) acc[i][j] = MFMA(pa[i], qb[j], acc[i][j]);
    }
#pragma unroll
    for (int i = 0; i < 2; ++i)
#pragma unroll
        for (int j = 0; j < 4; ++j) {
            int Rb = m0 + mq + 16 * i + qd * 4;
            int o = Rb >> 6, y = Rb & 63;
            int xo = 16 * j + fr;
            ushort4 pk;
            pk.x = bfr(acc[i][j][0]); pk.y = bfr(acc[i][j][1]);
            pk.z = bfr(acc[i][j][2]); pk.w = bfr(acc[i][j][3]);
            *(ushort4*)&X2[(long)z2 * 524288 + ((long)xo * 128 + o) * 64 + y] = pk;
        }
}

__global__ __launch_bounds__(256, 2) void k_idct2(const u16* __restrict__ X2, const u16* __restrict__ AcT,
                                                  const float* __restrict__ b1, u16* __restrict__ h1) {
    __shared__ __align__(16) short Pt[128 * 72];
    __shared__ __align__(16) short Qt[64 * 72];
    const int b = blockIdx.z, br = blockIdx.y, m0 = blockIdx.x * 128;
    const int z2 = br * 8 + b;
    const int tid = threadIdx.x;
    const int lane = tid & 63, wave = tid >> 6;
    const int fr = lane & 15, qd = lane >> 4;
    const int mq = wave * 32;
    const u16* Pg = X2 + (long)z2 * 524288 + (long)m0 * 64;
    f32x4 acc[2][4];
#pragma unroll
    for (int i = 0; i < 2; ++i)
#pragma unroll
        for (int j = 0; j < 4; ++j) acc[i][j] = (f32x4){0.f, 0.f, 0.f, 0.f};
#pragma unroll
    for (int j = 0; j < 4; ++j) {
        int idx = tid + j * 256;
        int r = idx >> 3, q8 = (idx & 7) * 8;
        *(s16x8*)&Pt[r * 72 + q8] = *(const s16x8*)&Pg[(long)r * 64 + q8];
    }
#pragma unroll
    for (int j = 0; j < 2; ++j) {
        int idx = tid + j * 256;
        int r = idx >> 3, q8 = (idx & 7) * 8;
        *(s16x8*)&Qt[r * 72 + q8] = *(const s16x8*)&AcT[(long)r * 64 + q8];
    }
    __syncthreads();
#pragma unroll
    for (int ks = 0; ks < 2; ++ks) {
        s16x8 pa[2], qb[4];
#pragma unroll
        for (int i = 0; i < 2; ++i) pa[i] = *(const s16x8*)&Pt[(mq + 16 * i + fr) * 72 + ks * 32 + qd * 8];
#pragma unroll
        for (int j = 0; j < 4; ++j) qb[j] = *(const s16x8*)&Qt[(16 * j + fr) * 72 + ks * 32 + qd * 8];
#pragma unroll
        for (int i = 0; i < 2; ++i)
#pragma unroll
            for (int j = 0; j < 4; ++j) acc[i][j] = MFMA(pa[i], qb[j], acc[i][j]);
    }
#pragma unroll
    for (int i = 0; i < 2; ++i)
#pragma unroll
        for (int j = 0; j < 4; ++j) {
            int Rb = m0 + mq + 16 * i + qd * 4;
            int xo = Rb >> 7, o = Rb & 127;
            int yo = 16 * j + fr;
            ushort4 pk;
            const float* bg = b1 + br * 128 + o;
            pk.x = bfr(fmaxf(acc[i][j][0] + bg[0], 0.f));
            pk.y = bfr(fmaxf(acc[i][j][1] + bg[1], 0.f));
            pk.z = bfr(fmaxf(acc[i][j][2] + bg[2], 0.f));
            pk.w = bfr(fmaxf(acc[i][j][3] + bg[3], 0.f));
            *(ushort4*)&h1[(long)z2 * 524288 + ((long)yo * 64 + xo) * 128 + o] = pk;
        }
}

// ---------------- conv2: implicit GEMM, h1 NHWC bf16, dil=2 pad=2 ----------------
__global__ __launch_bounds__(256, 2) void k_conv2(const u16* __restrict__ h1, const u16* __restrict__ W2a,
                                                  const float* __restrict__ b2, u16* __restrict__ h2) {
    __shared__ __align__(16) short Pt[128 * 40];
    __shared__ __align__(16) short Qt[128 * 40];
    const int b = blockIdx.z, br = blockIdx.y, y0 = blockIdx.x * 2;
    const int z2 = br * 8 + b;
    const int tid = threadIdx.x;
    const int lane = tid & 63, wave = tid >> 6;
    const int fr = lane & 15, qd = lane >> 4;
    const int mq = (wave >> 1) * 64, nq = (wave & 1) * 64;
    f32x4 acc[4][4];
#pragma unroll
    for (int i = 0; i < 4; ++i)
#pragma unroll
        for (int j = 0; j < 4; ++j) acc[i][j] = (f32x4){0.f, 0.f, 0.f, 0.f};
    const u16* hb = h1 + (long)z2 * 524288;
    const u16* Qg = W2a + (long)br * 147456;
    for (int ch = 0; ch < 36; ++ch) {
        const int t9 = ch >> 2, ci0 = (ch & 3) * 32;
        const int ky = t9 / 3, kx = t9 - 3 * ky;
        const int dy = 2 * ky - 2, dx = 2 * kx - 2;
        __syncthreads();
#pragma unroll
        for (int j = 0; j < 2; ++j) {
            int idx = tid + j * 256;
            int r = idx >> 2, q4 = (idx & 3) * 8;
            int ry = r >> 6, x = r & 63;
            int ysrc = y0 + ry + dy, xsrc = x + dx;
            s16x8 v = {0, 0, 0, 0, 0, 0, 0, 0};
            if ((unsigned)ysrc < 64u && (unsigned)xsrc < 64u)
                v = *(const s16x8*)&hb[((long)ysrc * 64 + xsrc) * 128 + ci0 + q4];
            *(s16x8*)&Pt[r * 40 + q4] = v;
            *(s16x8*)&Qt[r * 40 + q4] = *(const s16x8*)&Qg[(long)r * 1152 + ch * 32 + q4];
        }
        __syncthreads();
        s16x8 pa[4], qb[4];
#pragma unroll
        for (int i = 0; i < 4; ++i) {
            pa[i] = *(const s16x8*)&Pt[(mq + 16 * i + fr) * 40 + qd * 8];
            qb[i] = *(const s16x8*)&Qt[(nq + 16 * i + fr) * 40 + qd * 8];
        }
#pragma unroll
        for (int i = 0; i < 4; ++i)
#pragma unroll
            for (int j = 0; j < 4; ++j) acc[i][j] = MFMA(pa[i], qb[j], acc[i][j]);
    }
#pragma unroll
    for (int i = 0; i < 4; ++i)
#pragma unroll
        for (int j = 0; j < 4; ++j) {
            int rowb = mq + 16 * i + qd * 4;   // pixel within 2-row strip
            int o = nq + 16 * j + fr;
            float bb = b2[br * 128 + o];
#pragma unroll
            for (int r = 0; r < 4; ++r) {
                float v = fmaxf(acc[i][j][r] + bb, 0.f);
                h2[(long)z2 * 524288 + ((long)y0 * 64 + rowb + r) * 128 + o] = bfr(v);
            }
        }
}

// ---------------- conv3: h2 NHWC bf16 x W3 -> out NCHW fp32 (+bias+relu) ----------------
__global__ __launch_bounds__(256, 2) void k_conv3(const u16* __restrict__ h2, const u16* __restrict__ W3b,
                                                  const float* __restrict__ b3, float* __restrict__ out) {
    __shared__ __align__(16) short Pt[128 * 40];
    __shared__ __align__(16) short Qt[128 * 40];
    const int b = blockIdx.z, br = blockIdx.y, p0 = blockIdx.x * 128;
    const int z2 = br * 8 + b;
    const int tid = threadIdx.x;
    const int lane = tid & 63, wave = tid >> 6;
    const int fr = lane & 15, qd = lane >> 4;
    const int mq = (wave >> 1) * 64, nq = (wave & 1) * 64;
    f32x4 acc[4][4];
#pragma unroll
    for (int i = 0; i < 4; ++i)
#pragma unroll
        for (int j = 0; j < 4; ++j) acc[i][j] = (f32x4){0.f, 0.f, 0.f, 0.f};
    const u16* Pg = h2 + (long)z2 * 524288 + (long)p0 * 128;
    const u16* Qg = W3b + (long)br * 16384;
    for (int ch = 0; ch < 4; ++ch) {
        const int k0 = ch * 32;
        __syncthreads();
#pragma unroll
        for (int j = 0; j < 2; ++j) {
            int idx = tid + j * 256;
            int r = idx >> 2, q4 = (idx & 3) * 8;
            *(s16x8*)&Pt[r * 40 + q4] = *(const s16x8*)&Pg[(long)r * 128 + k0 + q4];
            *(s16x8*)&Qt[r * 40 + q4] = *(const s16x8*)&Qg[(long)r * 128 + k0 + q4];
        }
        __syncthreads();
        s16x8 pa[4], qb[4];
#pragma unroll
        for (int i = 0; i < 4; ++i) {
            pa[i] = *(const s16x8*)&Pt[(mq + 16 * i + fr) * 40 + qd * 8];
            qb[i] = *(const s16x8*)&Qt[(nq + 16 * i + fr) * 40 + qd * 8];
        }
#pragma unroll
        for (int i = 0; i < 4; ++i)
#pragma unroll
            for (int j = 0; j < 4; ++j) acc[i][j] = MFMA(pa[i], qb[j], acc[i][j]);
    }
#pragma unroll
    for (int i = 0; i < 4; ++i)
#pragma unroll
        for (int j = 0; j < 4; ++j) {
            int rowb = mq + 16 * i + qd * 4;
            int o = nq + 16 * j + fr;
            float bb = b3[br * 128 + o];
            float4 v = make_float4(fmaxf(acc[i][j][0] + bb, 0.f), fmaxf(acc[i][j][1] + bb, 0.f),
                                   fmaxf(acc[i][j][2] + bb, 0.f), fmaxf(acc[i][j][3] + bb, 0.f));
            *(float4*)&out[((long)b * 512 + br * 128 + o) * 4096 + p0 + rowb] = v;
        }
}

// ---------------- softmax gating + residual (NCHW, in-place on out) ----------------
__global__ __launch_bounds__(256) void k_final(const float* __restrict__ x, float* __restrict__ io) {
    const int bm = blockIdx.x;
    const int b = bm >> 6, m = bm & 63;
    const int n = threadIdx.x & 63, grp = threadIdx.x >> 6;
    const long base = ((long)b * 512) * 4096 + m * 64 + n;
    __shared__ float red[4][64];
    float mx = -1e30f;
    for (int c = grp * 128; c < grp * 128 + 128; ++c)
        mx = fmaxf(mx, io[base + (long)c * 4096]);
    red[grp][n] = mx;
    __syncthreads();
    const float M = fmaxf(fmaxf(red[0][n], red[1][n]), fmaxf(red[2][n], red[3][n]));
    __syncthreads();
    float s = 0.f;
    for (int c = grp * 128; c < grp * 128 + 128; ++c)
        s += __expf(io[base + (long)c * 4096] - M);
    red[grp][n] = s;
    __syncthreads();
    const float S = red[0][n] + red[1][n] + red[2][n] + red[3][n];
    const float inv = 1.0f / S;
    for (int c = grp * 128; c < grp * 128 + 128; ++c) {
        long a = base + (long)c * 4096;
        float w = __expf(io[a] - M) * inv;
        float xv = x[a];
        io[a] = xv * w + xv;
    }
}

// ---------------------------------------------------------------------------
extern "C" void kernel_launch(void* const* d_in, const int* in_sizes, int n_in,
                              void* d_out, int out_size, void* d_ws, size_t ws_size,
                              hipStream_t stream) {
    (void)in_sizes; (void)n_in; (void)out_size; (void)ws_size;
    const float* x  = (const float*)d_in[0];
    const float* W1 = (const float*)d_in[1];
    const float* b1 = (const float*)d_in[2];
    const float* W2 = (const float*)d_in[3];
    const float* b2 = (const float*)d_in[4];
    const float* W3 = (const float*)d_in[5];
    const float* b3 = (const float*)d_in[6];
    float* out = (float*)d_out;
    float* ws = (float*)d_ws;

    float* t    = ws + OFF_T;
    u16*   h1pre= (u16*)(ws + OFF_H1P);
    u16*   X2   = (u16*)(ws + OFF_X2);
    u16*   thi  = (u16*)(ws + OFF_THI);
    u16*   tlo  = (u16*)(ws + OFF_TLO);
    u16*   h1   = (u16*)(ws + OFF_H1);
    float* D    = ws + OFF_D;
    u16*   h2   = (u16*)(ws + OFF_H2);
    float* Ak   = ws + OFF_AK;
    u16*   Akh  = (u16*)(ws + OFF_AKH);
    u16*   Akl  = (u16*)(ws + OFF_AKL);
    u16*   AcT  = (u16*)(ws + OFF_ACT);
    u16*   Gb   = (u16*)(ws + OFF_GBF);
    u16*   W2a  = (u16*)(ws + OFF_W2A);
    u16*   W3b  = (u16*)(ws + OFF_W3B);
    unsigned* hist1 = (unsigned*)(ws + OFF_HIST);
    unsigned* hist2 = hist1 + 4096;
    unsigned* hist3 = hist2 + 4096;
    unsigned* sel   = (unsigned*)(ws + OFF_SEL);
    float* thr      = ws + OFF_THR;
    float* Ac       = ws + OFF_AC;

    k_build_mats<<<1024, 256, 0, stream>>>(Ak, Akh, Akl, AcT, Ac);
    k_zero<<<40, 256, 0, stream>>>(hist1, 10240);
    k_G_bf<<<1024, 256, 0, stream>>>(W1, Ak, Gb);
    k_wprep<<<2304, 256, 0, stream>>>(W2, W3, W2a, W3b);

    // forward spatial DCT (fp32) -> t NCHW
    k_tile_fwd<<<4096, 256, 0, stream>>>(x, t, Ac);
    // transpose + split to NHWC bf16
    k_tsplit<<<dim3(64, 8, 8), 256, 0, stream>>>(t, thi, tlo);
    // C-axis DCT via split-bf16 MFMA -> D fp32 NHWC
    k_cgemm<<<dim3(4, 32, 8), 256, 0, stream>>>(thi, tlo, Akh, Akl, D);

    // exact top-k thresholds
    k_hist1<<<256, 256, 0, stream>>>((const float4*)D, hist1);
    k_scan1<<<1, 256, 0, stream>>>(hist1, sel);
    k_hist2<<<256, 256, 0, stream>>>((const float4*)D, sel, hist2);
    k_scan2<<<1, 256, 0, stream>>>(hist2, sel);
    k_hist3<<<256, 256, 0, stream>>>((const float4*)D, sel, hist3);
    k_scan3<<<1, 256, 0, stream>>>(hist3, sel, thr);

    // branches (all 4 concurrent via grid.y)
    k_conv1<<<dim3(32, 4, 8), 256, 0, stream>>>(D, Gb, thr, h1pre);
    k_idct1<<<dim3(64, 4, 8), 256, 0, stream>>>(h1pre, AcT, X2);
    k_idct2<<<dim3(64, 4, 8), 256, 0, stream>>>(X2, AcT, b1, h1);
    k_conv2<<<dim3(32, 4, 8), 256, 0, stream>>>(h1, W2a, b2, h2);
    k_conv3<<<dim3(32, 4, 8), 256, 0, stream>>>(h2, W3b, b3, out);

    k_final<<<512, 256, 0, stream>>>(x, out);
}